// Round 3
// baseline (142.432 us; speedup 1.0000x reference)
//
#include <hip/hip_runtime.h>

// FVNet: B=8, F=512, N=512, K=32, fp32.
// Round 3: 2 dispatches.
//  K1 (k_a): logits GEMM (4n x 8k register tile, 16-way f-split, XOR-swizzled
//      W staging, global->reg prefetch pipeline) + shuffle softmax + a + asum
//      partials. Also zeroes K2's rendezvous counters.
//  K2 (k_ax_fv): ax/ax2 partial GEMMs (XOR-swizzled x^T staging) + 8-block
//      rendezvous per (b,ftile) via device-scope atomics + fused fv epilogue
//      (per-b global l2norm == 1/sqrt(512) analytically: all 512 K-rows are
//      unit-norm after the first normalization and are O(10), never near the
//      1e-12 clamp).
// ws floats: aP[131072] | axP[1048576] | ax2P[1048576] | asumP[8192] | ctr[32]

#define B_ 8
#define F_ 512
#define N_ 512
#define K_ 32

// ---------------- K1: logits + softmax + a + asumP ----------------
// grid = B * 32 ntiles (16 n) = 256 blocks, 256 threads.
// Threads: fs = t>>4 (16 f-split), kg = (t>>2)&3 (8 k), ng = t&3 (4 n).
__global__ __launch_bounds__(256) void k_a(const float* __restrict__ x,
                                           const float* __restrict__ W,
                                           const float* __restrict__ bias,
                                           float* __restrict__ aP,
                                           float* __restrict__ asumP,
                                           unsigned int* __restrict__ ctr) {
  __shared__ float xs[128][18];     // [f][n], mild (<=3-way) conflicts only
  __shared__ float ws[128 * 32];    // [f][k ^ (f&31)] XOR-swizzled, no pad
  __shared__ float red2[16][516];   // [fs][row*32+k] partial dump
  __shared__ float sm4[4][32];      // per-wave asum partials
  const int t = threadIdx.x;
  if (blockIdx.x == 0 && t < 32) ctr[t] = 0u;   // K2 rendezvous counters

  const int b  = blockIdx.x >> 5;
  const int nt = blockIdx.x & 31;
  const int n0 = nt << 4;
  const int ng = t & 3;
  const int kg = (t >> 2) & 3;
  const int fs = t >> 4;
  const int n4 = ng * 4;
  const int k8 = kg * 8;

  float acc[4][8];
#pragma unroll
  for (int i = 0; i < 4; ++i)
#pragma unroll
    for (int j = 0; j < 8; ++j) acc[i][j] = 0.f;

  float xr[8], wr[16];
  // ---- prefetch phase 0 ----
#pragma unroll
  for (int it = 0; it < 8; ++it) {
    int flat = t + 256 * it;
    xr[it] = x[(size_t)(b * F_ + (flat >> 4)) * N_ + n0 + (flat & 15)];
  }
#pragma unroll
  for (int it = 0; it < 16; ++it) {
    int flat = t + 256 * it;
    wr[it] = W[(flat >> 7) * F_ + (flat & 127)];
  }
  // store phase 0
#pragma unroll
  for (int it = 0; it < 8; ++it) {
    int flat = t + 256 * it;
    xs[flat >> 4][flat & 15] = xr[it];
  }
#pragma unroll
  for (int it = 0; it < 16; ++it) {
    int flat = t + 256 * it;
    int f = flat & 127, k = flat >> 7;
    ws[f * 32 + (k ^ (f & 31))] = wr[it];
  }
  __syncthreads();

  for (int ph = 0; ph < 4; ++ph) {
    // prefetch next phase into registers (overlaps with compute below)
    if (ph < 3) {
      const int fb = (ph + 1) << 7;
#pragma unroll
      for (int it = 0; it < 8; ++it) {
        int flat = t + 256 * it;
        xr[it] = x[(size_t)(b * F_ + fb + (flat >> 4)) * N_ + n0 + (flat & 15)];
      }
#pragma unroll
      for (int it = 0; it < 16; ++it) {
        int flat = t + 256 * it;
        wr[it] = W[(flat >> 7) * F_ + fb + (flat & 127)];
      }
    }
    // compute: 8 f per thread, tile 4n x 8k
#pragma unroll
    for (int fi = 0; fi < 8; ++fi) {
      const int f = fs * 8 + fi;
      const float2 x01 = *(const float2*)&xs[f][n4];
      const float2 x23 = *(const float2*)&xs[f][n4 + 2];
      const float4 wA = *(const float4*)&ws[f * 32 + ((k8) ^ (f & 28))];
      const float4 wB = *(const float4*)&ws[f * 32 + ((k8 + 4) ^ (f & 28))];
      const float xv[4] = {x01.x, x01.y, x23.x, x23.y};
      const float wa[4] = {((const float*)&wA)[0 ^ (fi & 3)],
                           ((const float*)&wA)[1 ^ (fi & 3)],
                           ((const float*)&wA)[2 ^ (fi & 3)],
                           ((const float*)&wA)[3 ^ (fi & 3)]};
      const float wb[4] = {((const float*)&wB)[0 ^ (fi & 3)],
                           ((const float*)&wB)[1 ^ (fi & 3)],
                           ((const float*)&wB)[2 ^ (fi & 3)],
                           ((const float*)&wB)[3 ^ (fi & 3)]};
#pragma unroll
      for (int i = 0; i < 4; ++i)
#pragma unroll
        for (int j = 0; j < 4; ++j) {
          acc[i][j]     += xv[i] * wa[j];
          acc[i][4 + j] += xv[i] * wb[j];
        }
    }
    __syncthreads();
    if (ph < 3) {
#pragma unroll
      for (int it = 0; it < 8; ++it) {
        int flat = t + 256 * it;
        xs[flat >> 4][flat & 15] = xr[it];
      }
#pragma unroll
      for (int it = 0; it < 16; ++it) {
        int flat = t + 256 * it;
        int f = flat & 127, k = flat >> 7;
        ws[f * 32 + (k ^ (f & 31))] = wr[it];
      }
      __syncthreads();
    }
  }

  // ---- dump partials (vectorized, conflict-spread) ----
#pragma unroll
  for (int i = 0; i < 4; ++i) {
    float4 v1, v2;
    v1.x = acc[i][0]; v1.y = acc[i][1]; v1.z = acc[i][2]; v1.w = acc[i][3];
    v2.x = acc[i][4]; v2.y = acc[i][5]; v2.z = acc[i][6]; v2.w = acc[i][7];
    *(float4*)&red2[fs][(n4 + i) * 32 + k8] = v1;
    *(float4*)&red2[fs][(n4 + i) * 32 + k8 + 4] = v2;
  }
  __syncthreads();

  // ---- combine 16 f-splits; thread owns outputs o0=2t, o0+1 ----
  const int o0 = 2 * t;
  const int row = t >> 4;        // 0..15 (n within tile)
  const int k0 = o0 & 31;
  float l0 = bias[k0], l1 = bias[k0 + 1];
#pragma unroll
  for (int s2 = 0; s2 < 16; ++s2) {
    float2 r = *(const float2*)&red2[s2][o0];
    l0 += r.x; l1 += r.y;
  }
  // ---- softmax over 32 k (16-lane group shuffles) ----
  float m = fmaxf(l0, l1);
  m = fmaxf(m, __shfl_xor(m, 1));
  m = fmaxf(m, __shfl_xor(m, 2));
  m = fmaxf(m, __shfl_xor(m, 4));
  m = fmaxf(m, __shfl_xor(m, 8));
  const float e0 = __expf(l0 - m), e1 = __expf(l1 - m);
  float ssum = e0 + e1;
  ssum += __shfl_xor(ssum, 1);
  ssum += __shfl_xor(ssum, 2);
  ssum += __shfl_xor(ssum, 4);
  ssum += __shfl_xor(ssum, 8);
  const float inv = 1.f / ssum;
  const float a0 = e0 * inv, a1 = e1 * inv;
  float2 av; av.x = a0; av.y = a1;
  *(float2*)&aP[(size_t)(b * N_ + n0 + row) * K_ + k0] = av;

  // ---- asum partials: reduce over 16 rows (wave shuffles + LDS) ----
  float s0 = a0 + __shfl_xor(a0, 16); s0 += __shfl_xor(s0, 32);
  float s1 = a1 + __shfl_xor(a1, 16); s1 += __shfl_xor(s1, 32);
  const int l = t & 63, w = t >> 6;
  if (l < 16) { sm4[w][2 * l] = s0; sm4[w][2 * l + 1] = s1; }
  __syncthreads();
  if (t < 32) {
    float tot = sm4[0][t] + sm4[1][t] + sm4[2][t] + sm4[3][t];
    asumP[(b * 32 + nt) * 32 + t] = tot;
  }
}

// ---------------- K2: ax/ax2 partials + rendezvous + fused fv ----------
// grid = B * 4 ftiles(128 f) * 8 nsplits(64 n) = 256 blocks, 256 threads.
__global__ __launch_bounds__(256) void k_ax_fv(const float* __restrict__ x,
                                               const float* __restrict__ aP,
                                               const float* __restrict__ asumP,
                                               const float* __restrict__ mu,
                                               const float* __restrict__ sg,
                                               float* __restrict__ axP,
                                               float* __restrict__ ax2P,
                                               unsigned int* __restrict__ ctr,
                                               float* __restrict__ out) {
  __shared__ float xsT[64 * 128];   // [n][f ^ (n&31)] XOR-swizzled
  __shared__ float as_[64][36];     // [n][k] (already conflict-free)
  __shared__ float sm[32];
  const int t  = threadIdx.x;
  const int s  = blockIdx.x & 7;
  const int ft = (blockIdx.x >> 3) & 3;
  const int b  = blockIdx.x >> 5;
  const int f0 = ft << 7;
  const int n0 = s << 6;
  const int fg = t >> 3, kg = t & 7;
  const int f4 = fg * 4, k4 = kg * 4;

  // stage x[b, f0:f0+128, n0:n0+64] transposed+swizzled (conflict-free)
#pragma unroll
  for (int it = 0; it < 32; ++it) {
    int flat = t + 256 * it;
    int f = flat >> 6, nn = flat & 63;
    xsT[nn * 128 + (f ^ (nn & 31))] =
        x[(size_t)(b * F_ + f0 + f) * N_ + n0 + nn];
  }
#pragma unroll
  for (int it = 0; it < 8; ++it) {
    int flat = t + 256 * it;
    int r = flat >> 5, kk = flat & 31;
    as_[r][kk] = aP[(size_t)(b * N_ + n0 + r) * K_ + kk];
  }
  __syncthreads();

  float ax[4][4] = {{0.f}}, bx[4][4] = {{0.f}};
#pragma unroll 2
  for (int nb = 0; nb < 64; nb += 4) {
#pragma unroll
    for (int u = 0; u < 4; ++u) {
      const int n = nb + u;
      const float4 xv = *(const float4*)&xsT[n * 128 + (f4 ^ (n & 28))];
      const float4 av = *(const float4*)&as_[n][k4];
      const float* xp = (const float*)&xv;
      const float* ap = (const float*)&av;
#pragma unroll
      for (int i = 0; i < 4; ++i) {
        const float xi = xp[i ^ u];   // undo within-chunk permutation
        const float xq = xi * xi;
#pragma unroll
        for (int j = 0; j < 4; ++j) {
          ax[i][j] += xi * ap[j];
          bx[i][j] += xq * ap[j];
        }
      }
    }
  }

  const size_t pbase = ((size_t)(s * B_ + b) * F_ + f0 + f4) * K_ + k4;
#pragma unroll
  for (int i = 0; i < 4; ++i) {
    float4 v1, v2;
    v1.x = ax[i][0]; v1.y = ax[i][1]; v1.z = ax[i][2]; v1.w = ax[i][3];
    v2.x = bx[i][0]; v2.y = bx[i][1]; v2.z = bx[i][2]; v2.w = bx[i][3];
    *(float4*)&axP [pbase + (size_t)i * K_] = v1;
    *(float4*)&ax2P[pbase + (size_t)i * K_] = v2;
  }

  // ---- rendezvous: 8 blocks of group (b,ft) ----
  __threadfence();
  __syncthreads();
  if (t == 0) {
    unsigned int* c = &ctr[b * 4 + ft];
    atomicAdd(c, 1u);
    while (__hip_atomic_load(c, __ATOMIC_ACQUIRE, __HIP_MEMORY_SCOPE_AGENT) < 8u)
      __builtin_amdgcn_s_sleep(2);
  }
  __syncthreads();
  __threadfence();   // acquire side: invalidate stale lines before partial reads

  // ---- fused fv epilogue: this block handles f in [f0+s*16, f0+s*16+16) ----
  if (t < 32) {
    float tot = 0.f;
#pragma unroll
    for (int nt = 0; nt < 32; ++nt) tot += asumP[(b * 32 + nt) * 32 + t];
    sm[t] = tot;
  }
  __syncthreads();

  const int k  = t & 31;
  const int fl = t >> 5;   // 0..7
#pragma unroll
  for (int c = 0; c < 2; ++c) {
    const int f = f0 + s * 16 + c * 8 + fl;
    float axv = 0.f, ax2v = 0.f;
#pragma unroll
    for (int sl = 0; sl < 8; ++sl) {
      const size_t idx = ((size_t)(sl * B_ + b) * F_ + f) * K_ + k;
      axv  += axP[idx];
      ax2v += ax2P[idx];
    }
    const float m  = mu[f * K_ + k];
    const float sd = sg[f * K_ + k];
    const float as = sm[k];
    const float fv1 = (axv - m * as) / sd;
    const float fv2 = (ax2v - 2.f * m * axv + m * m * as) / (sd * sd) - as;
    float s1 = fv1 * fv1, s2 = fv2 * fv2;
#pragma unroll
    for (int off = 16; off >= 1; off >>= 1) {
      s1 += __shfl_xor(s1, off);
      s2 += __shfl_xor(s2, off);
    }
    const float inv512 = 0.04419417382415922f;  // 1/sqrt(512)
    out[(size_t)b * 32768 + f * 32 + k] =
        fv1 / fmaxf(sqrtf(s1), 1e-12f) * inv512;
    out[(size_t)b * 32768 + 16384 + f * 32 + k] =
        fv2 / fmaxf(sqrtf(s2), 1e-12f) * inv512;
  }
}

extern "C" void kernel_launch(void* const* d_in, const int* in_sizes, int n_in,
                              void* d_out, int out_size, void* d_ws, size_t ws_size,
                              hipStream_t stream) {
  const float* x  = (const float*)d_in[0];
  const float* W  = (const float*)d_in[1];
  const float* bv = (const float*)d_in[2];
  const float* mu = (const float*)d_in[3];
  const float* sg = (const float*)d_in[4];
  float* out = (float*)d_out;

  float* ws    = (float*)d_ws;
  float* aP    = ws;                              // 131072
  float* axP   = ws + 131072;                     // 1048576
  float* ax2P  = ws + 131072 + 1048576;           // 1048576
  float* asumP = ws + 131072 + 2 * 1048576;       // 8192
  unsigned int* ctr = (unsigned int*)(asumP + 8192);  // 32

  hipLaunchKernelGGL(k_a, dim3(256), dim3(256), 0, stream,
                     x, W, bv, aP, asumP, ctr);
  hipLaunchKernelGGL(k_ax_fv, dim3(256), dim3(256), 0, stream,
                     x, aP, asumP, mu, sg, axP, ax2P, ctr, out);
}

// Round 4
// 85.045 us; speedup vs baseline: 1.6748x; 1.6748x over previous
//
#include <hip/hip_runtime.h>

// FVNet: B=8, F=512, N=512, K=32, fp32.
// Round 4: back to 3 dispatches (R3's cross-block rendezvous caused an
// agent-scope fence L2-invalidate storm: 18 MB re-read from HBM at 270 GB/s
// = 68 us. A kernel boundary is ONE implicit flush and far cheaper).
// Kept from R3: k_a register tile 4n x 8k + XOR-swizzled W staging + global->
// reg prefetch + shuffle softmax + fused asum partials; k_ax XOR-swizzled
// transpose staging. k_fv restored as its own dispatch.
//
// Per-b global l2norm == 1/sqrt(512) analytically: all 512 K-rows are
// unit-norm after the first normalization and row norms are O(10), never
// near the 1e-12 clamp.
// ws floats: aP[131072] | axP[1048576] | ax2P[1048576] | asumP[8192]

#define B_ 8
#define F_ 512
#define N_ 512
#define K_ 32

// ---------------- K1: logits + softmax + a + asumP ----------------
// grid = B * 32 ntiles (16 n) = 256 blocks, 256 threads.
// Threads: fs = t>>4 (16-way f-split), kg = (t>>2)&3 (8 k), ng = t&3 (4 n).
__global__ __launch_bounds__(256) void k_a(const float* __restrict__ x,
                                           const float* __restrict__ W,
                                           const float* __restrict__ bias,
                                           float* __restrict__ aP,
                                           float* __restrict__ asumP) {
  __shared__ float xs[128][18];     // [f][n], mild conflicts only
  __shared__ float ws[128 * 32];    // [f][k ^ (f&31)] XOR-swizzled, no pad
  __shared__ float red2[16][516];   // [fs][row*32+k] partial dump
  __shared__ float sm4[4][32];      // per-wave asum partials
  const int t = threadIdx.x;
  const int b  = blockIdx.x >> 5;
  const int nt = blockIdx.x & 31;
  const int n0 = nt << 4;
  const int ng = t & 3;
  const int kg = (t >> 2) & 3;
  const int fs = t >> 4;
  const int n4 = ng * 4;
  const int k8 = kg * 8;

  float acc[4][8];
#pragma unroll
  for (int i = 0; i < 4; ++i)
#pragma unroll
    for (int j = 0; j < 8; ++j) acc[i][j] = 0.f;

  float xr[8], wr[16];
  // ---- prefetch + store phase 0 ----
#pragma unroll
  for (int it = 0; it < 8; ++it) {
    int flat = t + 256 * it;
    xr[it] = x[(size_t)(b * F_ + (flat >> 4)) * N_ + n0 + (flat & 15)];
  }
#pragma unroll
  for (int it = 0; it < 16; ++it) {
    int flat = t + 256 * it;
    wr[it] = W[(flat >> 7) * F_ + (flat & 127)];
  }
#pragma unroll
  for (int it = 0; it < 8; ++it) {
    int flat = t + 256 * it;
    xs[flat >> 4][flat & 15] = xr[it];
  }
#pragma unroll
  for (int it = 0; it < 16; ++it) {
    int flat = t + 256 * it;
    int f = flat & 127, k = flat >> 7;
    ws[f * 32 + (k ^ (f & 31))] = wr[it];
  }
  __syncthreads();

  for (int ph = 0; ph < 4; ++ph) {
    if (ph < 3) {   // prefetch next phase into registers
      const int fb = (ph + 1) << 7;
#pragma unroll
      for (int it = 0; it < 8; ++it) {
        int flat = t + 256 * it;
        xr[it] = x[(size_t)(b * F_ + fb + (flat >> 4)) * N_ + n0 + (flat & 15)];
      }
#pragma unroll
      for (int it = 0; it < 16; ++it) {
        int flat = t + 256 * it;
        wr[it] = W[(flat >> 7) * F_ + fb + (flat & 127)];
      }
    }
#pragma unroll
    for (int fi = 0; fi < 8; ++fi) {
      const int f = fs * 8 + fi;
      const float2 x01 = *(const float2*)&xs[f][n4];
      const float2 x23 = *(const float2*)&xs[f][n4 + 2];
      const float4 wA = *(const float4*)&ws[f * 32 + ((k8) ^ (f & 28))];
      const float4 wB = *(const float4*)&ws[f * 32 + ((k8 + 4) ^ (f & 28))];
      const float xv[4] = {x01.x, x01.y, x23.x, x23.y};
      const float wa[4] = {((const float*)&wA)[0 ^ (fi & 3)],
                           ((const float*)&wA)[1 ^ (fi & 3)],
                           ((const float*)&wA)[2 ^ (fi & 3)],
                           ((const float*)&wA)[3 ^ (fi & 3)]};
      const float wb[4] = {((const float*)&wB)[0 ^ (fi & 3)],
                           ((const float*)&wB)[1 ^ (fi & 3)],
                           ((const float*)&wB)[2 ^ (fi & 3)],
                           ((const float*)&wB)[3 ^ (fi & 3)]};
#pragma unroll
      for (int i = 0; i < 4; ++i)
#pragma unroll
        for (int j = 0; j < 4; ++j) {
          acc[i][j]     += xv[i] * wa[j];
          acc[i][4 + j] += xv[i] * wb[j];
        }
    }
    __syncthreads();
    if (ph < 3) {
#pragma unroll
      for (int it = 0; it < 8; ++it) {
        int flat = t + 256 * it;
        xs[flat >> 4][flat & 15] = xr[it];
      }
#pragma unroll
      for (int it = 0; it < 16; ++it) {
        int flat = t + 256 * it;
        int f = flat & 127, k = flat >> 7;
        ws[f * 32 + (k ^ (f & 31))] = wr[it];
      }
      __syncthreads();
    }
  }

  // ---- dump partials ----
#pragma unroll
  for (int i = 0; i < 4; ++i) {
    float4 v1, v2;
    v1.x = acc[i][0]; v1.y = acc[i][1]; v1.z = acc[i][2]; v1.w = acc[i][3];
    v2.x = acc[i][4]; v2.y = acc[i][5]; v2.z = acc[i][6]; v2.w = acc[i][7];
    *(float4*)&red2[fs][(n4 + i) * 32 + k8] = v1;
    *(float4*)&red2[fs][(n4 + i) * 32 + k8 + 4] = v2;
  }
  __syncthreads();

  // ---- combine 16 f-splits; thread owns outputs o0=2t, o0+1 ----
  const int o0 = 2 * t;
  const int row = t >> 4;        // n within tile
  const int k0 = o0 & 31;
  float l0 = bias[k0], l1 = bias[k0 + 1];
#pragma unroll
  for (int s2 = 0; s2 < 16; ++s2) {
    float2 r = *(const float2*)&red2[s2][o0];
    l0 += r.x; l1 += r.y;
  }
  // ---- softmax over 32 k (16-lane group shuffles) ----
  float m = fmaxf(l0, l1);
  m = fmaxf(m, __shfl_xor(m, 1));
  m = fmaxf(m, __shfl_xor(m, 2));
  m = fmaxf(m, __shfl_xor(m, 4));
  m = fmaxf(m, __shfl_xor(m, 8));
  const float e0 = __expf(l0 - m), e1 = __expf(l1 - m);
  float ssum = e0 + e1;
  ssum += __shfl_xor(ssum, 1);
  ssum += __shfl_xor(ssum, 2);
  ssum += __shfl_xor(ssum, 4);
  ssum += __shfl_xor(ssum, 8);
  const float inv = 1.f / ssum;
  const float a0 = e0 * inv, a1 = e1 * inv;
  float2 av; av.x = a0; av.y = a1;
  *(float2*)&aP[(size_t)(b * N_ + n0 + row) * K_ + k0] = av;

  // ---- asum partials over the 16 rows ----
  float s0 = a0 + __shfl_xor(a0, 16); s0 += __shfl_xor(s0, 32);
  float s1 = a1 + __shfl_xor(a1, 16); s1 += __shfl_xor(s1, 32);
  const int l = t & 63, w = t >> 6;
  if (l < 16) { sm4[w][2 * l] = s0; sm4[w][2 * l + 1] = s1; }
  __syncthreads();
  if (t < 32) {
    float tot = sm4[0][t] + sm4[1][t] + sm4[2][t] + sm4[3][t];
    asumP[(b * 32 + nt) * 32 + t] = tot;
  }
}

// ---------------- K2: ax/ax2 partial GEMMs ----------------
// grid = B * 4 ftiles(128 f) * 8 nsplits(64 n) = 256 blocks, 256 threads.
// Threads: fg = t>>3 (4 f each), kg = t&7 (4 k each); 32 accumulators.
__global__ __launch_bounds__(256) void k_ax(const float* __restrict__ x,
                                            const float* __restrict__ aP,
                                            float* __restrict__ axP,
                                            float* __restrict__ ax2P) {
  __shared__ float xsT[64 * 128];   // [n][f ^ (n&31)] XOR-swizzled
  __shared__ float as_[64][36];     // [n][k]
  const int t  = threadIdx.x;
  const int s  = blockIdx.x & 7;
  const int ft = (blockIdx.x >> 3) & 3;
  const int b  = blockIdx.x >> 5;
  const int f0 = ft << 7;
  const int n0 = s << 6;
  const int fg = t >> 3, kg = t & 7;
  const int f4 = fg * 4, k4 = kg * 4;

  // stage x[b, f0:f0+128, n0:n0+64] transposed+swizzled (conflict-free)
#pragma unroll
  for (int it = 0; it < 32; ++it) {
    int flat = t + 256 * it;
    int f = flat >> 6, nn = flat & 63;
    xsT[nn * 128 + (f ^ (nn & 31))] =
        x[(size_t)(b * F_ + f0 + f) * N_ + n0 + nn];
  }
#pragma unroll
  for (int it = 0; it < 8; ++it) {
    int flat = t + 256 * it;
    int r = flat >> 5, kk = flat & 31;
    as_[r][kk] = aP[(size_t)(b * N_ + n0 + r) * K_ + kk];
  }
  __syncthreads();

  float ax[4][4] = {{0.f}}, bx[4][4] = {{0.f}};
#pragma unroll 2
  for (int nb = 0; nb < 64; nb += 4) {
#pragma unroll
    for (int u = 0; u < 4; ++u) {
      const int n = nb + u;
      const float4 xv = *(const float4*)&xsT[n * 128 + (f4 ^ (n & 28))];
      const float4 av = *(const float4*)&as_[n][k4];
      const float* xp = (const float*)&xv;
      const float* ap = (const float*)&av;
#pragma unroll
      for (int i = 0; i < 4; ++i) {
        const float xi = xp[i ^ u];   // undo within-chunk permutation
        const float xq = xi * xi;
#pragma unroll
        for (int j = 0; j < 4; ++j) {
          ax[i][j] += xi * ap[j];
          bx[i][j] += xq * ap[j];
        }
      }
    }
  }

  const size_t pbase = ((size_t)(s * B_ + b) * F_ + f0 + f4) * K_ + k4;
#pragma unroll
  for (int i = 0; i < 4; ++i) {
    float4 v1, v2;
    v1.x = ax[i][0]; v1.y = ax[i][1]; v1.z = ax[i][2]; v1.w = ax[i][3];
    v2.x = bx[i][0]; v2.y = bx[i][1]; v2.z = bx[i][2]; v2.w = bx[i][3];
    *(float4*)&axP [pbase + (size_t)i * K_] = v1;
    *(float4*)&ax2P[pbase + (size_t)i * K_] = v2;
  }
}

// ---------------- K3: fv1/fv2 + normalizations ----------------
// grid = 512 blocks, 1 thread per (b,f,k).
__global__ __launch_bounds__(256) void k_fv(const float* __restrict__ axP,
                                            const float* __restrict__ ax2P,
                                            const float* __restrict__ asumP,
                                            const float* __restrict__ mu,
                                            const float* __restrict__ sg,
                                            float* __restrict__ out) {
  __shared__ float sm[32];
  const int t = threadIdx.x;
  const int g = blockIdx.x * 256 + t;
  const int k = g & 31;
  const int f = (g >> 5) & (F_ - 1);
  const int b = g >> 14;

  if (t < 32) {  // block-wide asum[b][k] (b uniform per block)
    float s = 0.f;
#pragma unroll
    for (int nt = 0; nt < 32; ++nt) s += asumP[(b * 32 + nt) * 32 + t];
    sm[t] = s;
  }
  __syncthreads();

  float ax = 0.f, ax2 = 0.f;
#pragma unroll
  for (int s = 0; s < 8; ++s) {
    ax  += axP [(size_t)((s * B_ + b) * F_ + f) * K_ + k];
    ax2 += ax2P[(size_t)((s * B_ + b) * F_ + f) * K_ + k];
  }
  const float m  = mu[f * K_ + k];
  const float sd = sg[f * K_ + k];
  const float as = sm[k];

  const float fv1 = (ax - m * as) / sd;
  const float fv2 = (ax2 - 2.f * m * ax + m * m * as) / (sd * sd) - as;

  float s1 = fv1 * fv1, s2 = fv2 * fv2;
#pragma unroll
  for (int off = 16; off >= 1; off >>= 1) {
    s1 += __shfl_xor(s1, off, 32);
    s2 += __shfl_xor(s2, off, 32);
  }
  const float inv512 = 0.04419417382415922f;  // 1/sqrt(512)
  const float o1 = fv1 / fmaxf(sqrtf(s1), 1e-12f) * inv512;
  const float o2 = fv2 / fmaxf(sqrtf(s2), 1e-12f) * inv512;

  out[(size_t)b * (2 * F_ * K_) + f * K_ + k] = o1;
  out[(size_t)b * (2 * F_ * K_) + F_ * K_ + f * K_ + k] = o2;
}

extern "C" void kernel_launch(void* const* d_in, const int* in_sizes, int n_in,
                              void* d_out, int out_size, void* d_ws, size_t ws_size,
                              hipStream_t stream) {
  const float* x  = (const float*)d_in[0];
  const float* W  = (const float*)d_in[1];
  const float* bv = (const float*)d_in[2];
  const float* mu = (const float*)d_in[3];
  const float* sg = (const float*)d_in[4];
  float* out = (float*)d_out;

  float* ws    = (float*)d_ws;
  float* aP    = ws;                              // 131072
  float* axP   = ws + 131072;                     // 1048576
  float* ax2P  = ws + 131072 + 1048576;           // 1048576
  float* asumP = ws + 131072 + 2 * 1048576;       // 8192

  hipLaunchKernelGGL(k_a,  dim3(256), dim3(256), 0, stream, x, W, bv, aP, asumP);
  hipLaunchKernelGGL(k_ax, dim3(256), dim3(256), 0, stream, x, aP, axP, ax2P);
  hipLaunchKernelGGL(k_fv, dim3(512), dim3(256), 0, stream,
                     axP, ax2P, asumP, mu, sg, out);
}